// Round 5
// baseline (399.808 us; speedup 1.0000x reference)
//
#include <hip/hip_runtime.h>
#include <math.h>

#define T_SEQ 2048
#define D_MODEL 512
#define H_HEADS 8
#define HD 64
#define NCH 32      // number of chunks
#define CSZ 64      // chunk size  (NCH*CSZ == T_SEQ)
#define CAP 192     // max stored critical entries per row (generic count = 103)

// order-preserving float<->u32 key transforms
__device__ __forceinline__ unsigned f2k(float f) {
    unsigned u = __float_as_uint(f);
    return (u & 0x80000000u) ? ~u : (u | 0x80000000u);
}
__device__ __forceinline__ float k2f(unsigned k) {
    unsigned u = (k & 0x80000000u) ? (k & 0x7fffffffu) : ~k;
    return __uint_as_float(u);
}

// ---------------- K1: QKV projection (x @ W.T + b), head-major store + phi ----------------
// grid (32, 8, 3), block 256
__global__ __launch_bounds__(256) void proj_qkv_kernel(
    const float* __restrict__ x,
    const float* __restrict__ wq, const float* __restrict__ bq,
    const float* __restrict__ wk, const float* __restrict__ bk,
    const float* __restrict__ wv, const float* __restrict__ bv,
    float* __restrict__ qh, float* __restrict__ kh, float* __restrict__ vh,
    float* __restrict__ qf, float* __restrict__ kf)
{
    const int which = blockIdx.z;
    const float* W    = (which == 0) ? wq : (which == 1) ? wk : wv;
    const float* bias = (which == 0) ? bq : (which == 1) ? bk : bv;
    float* outh = (which == 0) ? qh : (which == 1) ? kh : vh;
    float* outf = (which == 0) ? qf : (which == 1) ? kf : nullptr;

    __shared__ float As[64][33];
    __shared__ float Bs[64][33];
    const int tid = threadIdx.x;
    const int m0 = blockIdx.x * 64;
    const int n0 = blockIdx.y * 64;
    const int rb = (tid >> 4) * 4;
    const int cb = (tid & 15) * 4;

    float acc[4][4] = {};
    for (int k0 = 0; k0 < D_MODEL; k0 += 32) {
        for (int l = 0; l < 2; ++l) {
            int p = tid + l * 256;          // 0..511 float4 slots (64 rows x 8)
            int row = p >> 3;
            int c4 = (p & 7) * 4;
            float4 av = *(const float4*)(x + (size_t)(m0 + row) * D_MODEL + k0 + c4);
            As[row][c4 + 0] = av.x; As[row][c4 + 1] = av.y;
            As[row][c4 + 2] = av.z; As[row][c4 + 3] = av.w;
            float4 wv4 = *(const float4*)(W + (size_t)(n0 + row) * D_MODEL + k0 + c4);
            Bs[row][c4 + 0] = wv4.x; Bs[row][c4 + 1] = wv4.y;
            Bs[row][c4 + 2] = wv4.z; Bs[row][c4 + 3] = wv4.w;
        }
        __syncthreads();
        #pragma unroll
        for (int kk = 0; kk < 32; ++kk) {
            float ar[4], br[4];
            #pragma unroll
            for (int i = 0; i < 4; ++i) ar[i] = As[rb + i][kk];
            #pragma unroll
            for (int j = 0; j < 4; ++j) br[j] = Bs[cb + j][kk];
            #pragma unroll
            for (int i = 0; i < 4; ++i)
                #pragma unroll
                for (int j = 0; j < 4; ++j)
                    acc[i][j] = fmaf(ar[i], br[j], acc[i][j]);
        }
        __syncthreads();
    }
    #pragma unroll
    for (int i = 0; i < 4; ++i) {
        int m = m0 + rb + i;
        #pragma unroll
        for (int j = 0; j < 4; ++j) {
            int n = n0 + cb + j;
            float v = acc[i][j] + bias[n];
            int h = n >> 6, d = n & 63;
            size_t idx = ((size_t)(h * T_SEQ) + m) * HD + d;
            outh[idx] = v;
            if (outf) outf[idx] = (v > 0.f) ? (v + 1.f) : expf(v);  // elu+1
        }
    }
}

// ---------------- K6: output projection (att @ wo.T + bo) ----------------
// grid (32, 8), block 256
__global__ __launch_bounds__(256) void out_proj_kernel(
    const float* __restrict__ att, const float* __restrict__ wo,
    const float* __restrict__ bo, float* __restrict__ out)
{
    __shared__ float As[64][33];
    __shared__ float Bs[64][33];
    const int tid = threadIdx.x;
    const int m0 = blockIdx.x * 64;
    const int n0 = blockIdx.y * 64;
    const int rb = (tid >> 4) * 4;
    const int cb = (tid & 15) * 4;

    float acc[4][4] = {};
    for (int k0 = 0; k0 < D_MODEL; k0 += 32) {
        for (int l = 0; l < 2; ++l) {
            int p = tid + l * 256;
            int row = p >> 3;
            int c4 = (p & 7) * 4;
            float4 av = *(const float4*)(att + (size_t)(m0 + row) * D_MODEL + k0 + c4);
            As[row][c4 + 0] = av.x; As[row][c4 + 1] = av.y;
            As[row][c4 + 2] = av.z; As[row][c4 + 3] = av.w;
            float4 wv4 = *(const float4*)(wo + (size_t)(n0 + row) * D_MODEL + k0 + c4);
            Bs[row][c4 + 0] = wv4.x; Bs[row][c4 + 1] = wv4.y;
            Bs[row][c4 + 2] = wv4.z; Bs[row][c4 + 3] = wv4.w;
        }
        __syncthreads();
        #pragma unroll
        for (int kk = 0; kk < 32; ++kk) {
            float ar[4], br[4];
            #pragma unroll
            for (int i = 0; i < 4; ++i) ar[i] = As[rb + i][kk];
            #pragma unroll
            for (int j = 0; j < 4; ++j) br[j] = Bs[cb + j][kk];
            #pragma unroll
            for (int i = 0; i < 4; ++i)
                #pragma unroll
                for (int j = 0; j < 4; ++j)
                    acc[i][j] = fmaf(ar[i], br[j], acc[i][j]);
        }
        __syncthreads();
    }
    #pragma unroll
    for (int i = 0; i < 4; ++i) {
        int m = m0 + rb + i;
        #pragma unroll
        for (int j = 0; j < 4; ++j) {
            int n = n0 + cb + j;
            out[(size_t)m * D_MODEL + n] = acc[i][j] + bo[n];
        }
    }
}

// ---------------- K2a: S = Q K^T / 8, per head, 64x64 tiles ----------------
// grid (32 jtile, 32 ttile, 8 head), block 256
__global__ __launch_bounds__(256) void qk_gemm_kernel(
    const float* __restrict__ qh, const float* __restrict__ kh, float* __restrict__ S)
{
    __shared__ float As[64][65];   // Q rows (t)
    __shared__ float Bs[64][65];   // K rows (j)
    const int tid = threadIdx.x;
    const int n0 = blockIdx.x * 64;   // key index j
    const int m0 = blockIdx.y * 64;   // query index t
    const int h  = blockIdx.z;
    const float* qb = qh + (size_t)h * T_SEQ * HD;
    const float* kb = kh + (size_t)h * T_SEQ * HD;

    for (int l = 0; l < 4; ++l) {
        int p = tid + l * 256;            // 1024 float4 = 64 rows x 16
        int row = p >> 4, c4 = (p & 15) * 4;
        float4 a = *(const float4*)(qb + (size_t)(m0 + row) * HD + c4);
        As[row][c4 + 0] = a.x; As[row][c4 + 1] = a.y; As[row][c4 + 2] = a.z; As[row][c4 + 3] = a.w;
        float4 b = *(const float4*)(kb + (size_t)(n0 + row) * HD + c4);
        Bs[row][c4 + 0] = b.x; Bs[row][c4 + 1] = b.y; Bs[row][c4 + 2] = b.z; Bs[row][c4 + 3] = b.w;
    }
    __syncthreads();

    const int rb = (tid >> 4) * 4;
    const int cb = (tid & 15) * 4;
    float acc[4][4] = {};
    #pragma unroll 16
    for (int kk = 0; kk < HD; ++kk) {
        float ar[4], br[4];
        #pragma unroll
        for (int i = 0; i < 4; ++i) ar[i] = As[rb + i][kk];
        #pragma unroll
        for (int j = 0; j < 4; ++j) br[j] = Bs[cb + j][kk];
        #pragma unroll
        for (int i = 0; i < 4; ++i)
            #pragma unroll
            for (int j = 0; j < 4; ++j)
                acc[i][j] = fmaf(ar[i], br[j], acc[i][j]);
    }
    #pragma unroll
    for (int i = 0; i < 4; ++i) {
        float4 o;
        o.x = acc[i][0] * 0.125f; o.y = acc[i][1] * 0.125f;
        o.z = acc[i][2] * 0.125f; o.w = acc[i][3] * 0.125f;
        *(float4*)(S + ((size_t)h * T_SEQ + m0 + rb + i) * T_SEQ + n0 + cb) = o;
    }
}

// ---------------- K2b: per-row exact quantiles + critical-list compaction ----------------
// grid (T_SEQ/4, 8), block 256; wave w handles row blockIdx.x*4 + w
// hist[] is WAVE-PRIVATE (indexed by r) -> no __syncthreads anywhere.
__global__ __launch_bounds__(256) void select_kernel(
    const float* __restrict__ S, float2* __restrict__ clist,
    int* __restrict__ critcnt, float* __restrict__ marg)
{
    const int h = blockIdx.y;
    const int r = threadIdx.x >> 6;
    const int lane = threadIdx.x & 63;
    const int t = blockIdx.x * 4 + r;
    __shared__ unsigned hist[4][2][256];

    const float* srow = S + ((size_t)h * T_SEQ + t) * T_SEQ;
    unsigned kr[32];
    #pragma unroll
    for (int u = 0; u < 8; ++u) {
        float4 f = *(const float4*)(srow + (size_t)(lane + u * 64) * 4);
        kr[u * 4 + 0] = f2k(f.x); kr[u * 4 + 1] = f2k(f.y);
        kr[u * 4 + 2] = f2k(f.z); kr[u * 4 + 3] = f2k(f.w);
    }

    const unsigned rankv[2] = {204u, 1944u};
    unsigned pfx[2] = {0u, 0u}, base[2] = {0u, 0u};
    for (int p = 0; p < 4; ++p) {
        const int sh = 24 - 8 * p;
        #pragma unroll
        for (int q = 0; q < 4; ++q) {
            hist[r][0][lane * 4 + q] = 0u;
            hist[r][1][lane * 4 + q] = 0u;
        }
        const bool dup = (p == 0) || (pfx[0] == pfx[1]);
        if (p == 0) {
            // concentrated digit: pre-merge equal bins across 16-lane groups
            // (survivors carry disjoint partial sums -> totals exact)
            #pragma unroll
            for (int u = 0; u < 32; ++u) {
                unsigned bin = kr[u] >> 24;
                unsigned cnt = 1u;
                #pragma unroll
                for (int off = 1; off <= 8; off <<= 1) {
                    unsigned ob = (unsigned)__shfl_xor((int)bin, off);
                    unsigned oc = (unsigned)__shfl_xor((int)cnt, off);
                    if (ob == bin) cnt = (lane & off) ? 0u : cnt + oc;
                }
                if (cnt) atomicAdd(&hist[r][0][bin], cnt);
            }
        } else {
            #pragma unroll
            for (int u = 0; u < 32; ++u) {
                unsigned k = kr[u];
                unsigned hi = k >> (sh + 8);
                unsigned bin = (k >> sh) & 255u;
                if (hi == pfx[0]) atomicAdd(&hist[r][0][bin], 1u);
                if (!dup && hi == pfx[1]) atomicAdd(&hist[r][1][bin], 1u);
            }
        }
        #pragma unroll
        for (int si = 0; si < 2; ++si) {
            const unsigned* hh = hist[r][dup ? 0 : si];
            unsigned c0 = hh[lane * 4 + 0], c1 = hh[lane * 4 + 1];
            unsigned c2 = hh[lane * 4 + 2], c3 = hh[lane * 4 + 3];
            unsigned lsum = c0 + c1 + c2 + c3;
            unsigned incl = lsum;
            #pragma unroll
            for (int off = 1; off < 64; off <<= 1) {
                unsigned tv = __shfl_up(incl, off);
                if (lane >= off) incl += tv;
            }
            unsigned e0 = incl - lsum;
            unsigned e1 = e0 + c0, e2 = e1 + c1, e3 = e2 + c2;
            unsigned rr = rankv[si] - base[si];
            int bin = -1; unsigned nb = 0u;
            if (rr >= e0 && rr < e0 + c0)      { bin = lane * 4 + 0; nb = e0; }
            else if (rr >= e1 && rr < e1 + c1) { bin = lane * 4 + 1; nb = e1; }
            else if (rr >= e2 && rr < e2 + c2) { bin = lane * 4 + 2; nb = e2; }
            else if (rr >= e3 && rr < e3 + c3) { bin = lane * 4 + 3; nb = e3; }
            unsigned long long bal = __ballot(bin >= 0);
            int src = __ffsll((unsigned long long)bal) - 1;
            bin = __shfl(bin, src);
            nb  = __shfl(nb, src);
            pfx[si] = (pfx[si] << 8) | (unsigned)bin;
            base[si] += nb;
        }
    }

    const unsigned kth0 = pfx[0], kth1 = pfx[1];
    unsigned cle0 = 0, cle1 = 0, mng0 = 0xffffffffu, mng1 = 0xffffffffu, mx = 0u;
    #pragma unroll
    for (int u = 0; u < 32; ++u) {
        unsigned k = kr[u];
        mx = max(mx, k);
        if (k <= kth0) cle0++; else mng0 = min(mng0, k);
        if (k <= kth1) cle1++; else mng1 = min(mng1, k);
    }
    #pragma unroll
    for (int off = 32; off > 0; off >>= 1) {
        cle0 += (unsigned)__shfl_xor(cle0, off);
        cle1 += (unsigned)__shfl_xor(cle1, off);
        mng0 = min(mng0, (unsigned)__shfl_xor(mng0, off));
        mng1 = min(mng1, (unsigned)__shfl_xor(mng1, off));
        mx   = max(mx,   (unsigned)__shfl_xor(mx, off));
    }
    const float v204  = k2f(kth0);
    const float v205  = (cle0 > 205u) ? v204 : k2f(mng0);
    const float v1944 = k2f(kth1);
    const float v1945 = (cle1 > 1945u) ? v1944 : k2f(mng1);
    const float skip_th = v204 * 0.30f + v205 * 0.70f;
    const float crit_th = v1944 * 0.35f + v1945 * 0.65f;
    const float m = k2f(mx);

    float z = 0.f; unsigned mc = 0u;
    #pragma unroll
    for (int u = 0; u < 32; ++u) {
        float sv = k2f(kr[u]);
        bool crit = sv > crit_th;
        bool skip = sv < skip_th;
        if (crit) z += __expf(sv - m);
        if (!crit && !skip) mc++;
    }
    #pragma unroll
    for (int off = 32; off > 0; off >>= 1) {
        z += __shfl_xor(z, off);
        mc += (unsigned)__shfl_xor(mc, off);
    }
    const float invz = (z > 0.f) ? (1.f / z) : 0.f;

    // ---- compact critical entries: (w*invz, j) pairs, deterministic order ----
    float2* lrow = clist + ((size_t)h * T_SEQ + t) * CAP;
    unsigned bcnt = 0;
    #pragma unroll
    for (int u8 = 0; u8 < 8; ++u8) {
        #pragma unroll
        for (int q = 0; q < 4; ++q) {
            float sv = k2f(kr[u8 * 4 + q]);
            bool crit = sv > crit_th;
            unsigned long long bal = __ballot(crit);
            if (crit) {
                unsigned pos = bcnt + (unsigned)__popcll(bal & ((lane == 0) ? 0ull : (~0ull >> (64 - lane))));
                if (pos < CAP) {
                    unsigned j = (unsigned)(4 * lane + 256 * u8 + q);
                    lrow[pos] = make_float2(__expf(sv - m) * invz, __uint_as_float(j));
                }
            }
            bcnt += (unsigned)__popcll(bal);
        }
    }
    if (lane == 0) {
        critcnt[(size_t)h * T_SEQ + t] = (int)min(bcnt, (unsigned)CAP);
        marg[(size_t)h * T_SEQ + t] = (float)mc * (1.f / (float)T_SEQ);
    }
    (void)skip_th;
}

// ---------------- K2c: gather crit_out from compacted lists; att += ----------------
// grid (T_SEQ/4, 8), block 256; wave per row
__global__ __launch_bounds__(256) void wv_gather_kernel(
    const float2* __restrict__ clist, const int* __restrict__ critcnt,
    const float* __restrict__ vh, float* __restrict__ att)
{
    const int h = blockIdx.y;
    const int r = threadIdx.x >> 6;
    const int lane = threadIdx.x & 63;
    const int t = blockIdx.x * 4 + r;
    const float* vb = vh + (size_t)h * T_SEQ * HD;
    const float2* lrow = clist + ((size_t)h * T_SEQ + t) * CAP;
    const int cnt = critcnt[(size_t)h * T_SEQ + t];

    float acc = 0.f;
    int i = 0;
    for (; i + 8 <= cnt; i += 8) {
        float2 e[8];
        #pragma unroll
        for (int q = 0; q < 8; ++q) e[q] = lrow[i + q];
        #pragma unroll
        for (int q = 0; q < 8; ++q) {
            unsigned j = __float_as_uint(e[q].y);
            acc = fmaf(e[q].x, vb[(size_t)j * HD + lane], acc);
        }
    }
    for (; i < cnt; ++i) {
        float2 e = lrow[i];
        unsigned j = __float_as_uint(e.y);
        acc = fmaf(e.x, vb[(size_t)j * HD + lane], acc);
    }
    att[(size_t)t * D_MODEL + h * HD + lane] += acc;
}

// ---------------- K3: per-chunk sums A_c = sum kf x v, b_c = sum kf ----------------
// grid (NCH, 8), block 256
__global__ __launch_bounds__(256) void chunk_sums_kernel(
    const float* __restrict__ kf, const float* __restrict__ vh,
    float* __restrict__ Ac, float* __restrict__ bc)
{
    const int c = blockIdx.x, h = blockIdx.y;
    const int tid = threadIdx.x;
    __shared__ float kfl[CSZ][HD];
    __shared__ float vl[CSZ][HD];
    const size_t base = ((size_t)h * T_SEQ + c * CSZ) * HD;

    for (int l = 0; l < 4; ++l) {
        int p = tid + l * 256;            // float4 index over 64x16
        int row = p >> 4, c4 = (p & 15) * 4;
        *(float4*)&kfl[row][c4] = *(const float4*)(kf + base + (size_t)row * HD + c4);
        *(float4*)&vl[row][c4]  = *(const float4*)(vh + base + (size_t)row * HD + c4);
    }
    __syncthreads();

    const int d = tid >> 2, e0 = (tid & 3) * 16;
    float acc[16] = {};
    for (int u = 0; u < CSZ; ++u) {
        float a = kfl[u][d];
        #pragma unroll
        for (int i = 0; i < 16; ++i) acc[i] = fmaf(a, vl[u][e0 + i], acc[i]);
    }
    float* Adst = Ac + (((size_t)(h * NCH + c) * HD + d) * HD + e0);
    #pragma unroll
    for (int i = 0; i < 16; ++i) Adst[i] = acc[i];

    if (tid < HD) {
        float sum = 0.f;
        for (int u = 0; u < CSZ; ++u) sum += kfl[u][tid];
        bc[(size_t)(h * NCH + c) * HD + tid] = sum;
    }
}

// ---------------- K4: exclusive prefix over chunks ----------------
// grid (8), block 256
__global__ __launch_bounds__(256) void prefix_kernel(
    const float* __restrict__ Ac, const float* __restrict__ bc,
    float* __restrict__ Sx, float* __restrict__ sx)
{
    const int h = blockIdx.x;
    const int tid = threadIdx.x;
    float run[16];
    #pragma unroll
    for (int i = 0; i < 16; ++i) run[i] = 0.f;
    for (int c = 0; c < NCH; ++c) {
        const float* a = Ac + (size_t)(h * NCH + c) * 4096;
        float* sdst = Sx + (size_t)(h * NCH + c) * 4096;
        #pragma unroll
        for (int i = 0; i < 16; ++i) {
            int idx = tid + i * 256;
            sdst[idx] = run[i];
            run[i] += a[idx];
        }
    }
    if (tid < HD) {
        float rb = 0.f;
        for (int c = 0; c < NCH; ++c) {
            sx[(size_t)(h * NCH + c) * HD + tid] = rb;
            rb += bc[(size_t)(h * NCH + c) * HD + tid];
        }
    }
}

// ---------------- K5: intra-chunk causal linear attention; WRITES att ----------------
// grid (NCH, 8), block 256
__global__ __launch_bounds__(256) void lin_combine_kernel(
    const float* __restrict__ qf, const float* __restrict__ kf, const float* __restrict__ vh,
    const float* __restrict__ Sx, const float* __restrict__ sx,
    const float* __restrict__ marg, float* __restrict__ att)
{
    const int c = blockIdx.x, h = blockIdx.y;
    const int tid = threadIdx.x;
    __shared__ float Qs[CSZ][65];
    __shared__ float Ks[CSZ][65];   // reused to hold Ss after P is computed
    __shared__ float P[CSZ][66];
    __shared__ float svv[HD];
    __shared__ float coef[CSZ];

    const size_t base = ((size_t)h * T_SEQ + c * CSZ) * HD;
    for (int l = 0; l < 4; ++l) {
        int p = tid + l * 256;
        int row = p >> 4, c4 = (p & 15) * 4;
        *(float4*)&Qs[row][c4] = *(const float4*)(qf + base + (size_t)row * HD + c4);
        *(float4*)&Ks[row][c4] = *(const float4*)(kf + base + (size_t)row * HD + c4);
    }
    if (tid < HD) svv[tid] = sx[(size_t)(h * NCH + c) * HD + tid];
    __syncthreads();

    // P[t][u] = qf_t . kf_u  (zero above diagonal)
    {
        const int tq = tid >> 2, u0 = (tid & 3) * 16;
        float pr[16];
        #pragma unroll
        for (int i = 0; i < 16; ++i) pr[i] = 0.f;
        for (int d = 0; d < HD; ++d) {
            float qv = Qs[tq][d];
            #pragma unroll
            for (int i = 0; i < 16; ++i) pr[i] = fmaf(qv, Ks[u0 + i][d], pr[i]);
        }
        #pragma unroll
        for (int i = 0; i < 16; ++i) P[tq][u0 + i] = (u0 + i <= tq) ? pr[i] : 0.f;
    }
    __syncthreads();

    // denominator + coefficient (threads 0..63), and load Ss into Ks (all threads)
    if (tid < CSZ) {
        const int tq = tid;
        float den = 0.f;
        for (int d = 0; d < HD; ++d) den += Qs[tq][d] * svv[d];
        for (int u = 0; u <= tq; ++u) den += P[tq][u];
        den = fmaxf(den, 1e-6f);
        coef[tq] = marg[(size_t)h * T_SEQ + c * CSZ + tq] / den;
    }
    {
        const float* Sbase = Sx + (size_t)(h * NCH + c) * 4096;
        for (int l = 0; l < 4; ++l) {
            int p = tid + l * 256;
            int row = p >> 4, c4 = (p & 15) * 4;
            *(float4*)&Ks[row][c4] = *(const float4*)(Sbase + (size_t)row * HD + c4);
        }
    }
    __syncthreads();

    // lin_num = qf @ Ss + P @ v ; write out scaled (att = )
    {
        const int tq = tid >> 2, e0 = (tid & 3) * 16;
        float acc[16];
        #pragma unroll
        for (int i = 0; i < 16; ++i) acc[i] = 0.f;
        for (int d = 0; d < HD; ++d) {
            float qv = Qs[tq][d];
            #pragma unroll
            for (int i = 0; i < 16; ++i) acc[i] = fmaf(qv, Ks[d][e0 + i], acc[i]);
        }
        const float* vb = vh + base;
        for (int u = 0; u <= tq; ++u) {
            float pv = P[tq][u];
            #pragma unroll
            for (int i = 0; i < 16; ++i) acc[i] = fmaf(pv, vb[(size_t)u * HD + e0 + i], acc[i]);
        }
        const float cf = coef[tq];
        float* dst = att + (size_t)(c * CSZ + tq) * D_MODEL + h * HD + e0;
        #pragma unroll
        for (int i = 0; i < 16; ++i) dst[i] = acc[i] * cf;
    }
}

extern "C" void kernel_launch(void* const* d_in, const int* in_sizes, int n_in,
                              void* d_out, int out_size, void* d_ws, size_t ws_size,
                              hipStream_t stream)
{
    const float* x  = (const float*)d_in[0];
    const float* wq = (const float*)d_in[1];
    const float* bq = (const float*)d_in[2];
    const float* wk = (const float*)d_in[3];
    const float* bk = (const float*)d_in[4];
    const float* wv = (const float*)d_in[5];
    const float* bv = (const float*)d_in[6];
    const float* wo = (const float*)d_in[7];
    const float* bo = (const float*)d_in[8];
    float* out = (float*)d_out;

    float* ws = (float*)d_ws;
    const size_t NTD = (size_t)T_SEQ * D_MODEL;         // 1M floats
    const size_t NSS = (size_t)H_HEADS * T_SEQ * T_SEQ; // 33.5M floats (134 MB)
    const size_t NROW = (size_t)H_HEADS * T_SEQ;        // 16384
    float* S    = ws;
    float* qh   = S + NSS;
    float* kh   = qh + NTD;
    float* vh   = kh + NTD;
    float* qf   = vh + NTD;
    float* kf   = qf + NTD;
    float* att  = kf + NTD;
    float* Ac   = att + NTD;
    float* Sx   = Ac + NTD;
    float* bc   = Sx + NTD;                 // 16384
    float* sx   = bc + 16384;               // 16384
    float* marg = sx + 16384;               // 16384
    float2* clist = (float2*)(marg + 16384);        // NROW*CAP float2
    int* critcnt  = (int*)(clist + NROW * CAP);     // NROW ints

    dim3 b256(256);
    proj_qkv_kernel<<<dim3(32, 8, 3), b256, 0, stream>>>(x, wq, bq, wk, bk, wv, bv,
                                                         qh, kh, vh, qf, kf);
    qk_gemm_kernel<<<dim3(32, 32, 8), b256, 0, stream>>>(qh, kh, S);
    select_kernel<<<dim3(T_SEQ / 4, H_HEADS), b256, 0, stream>>>(S, clist, critcnt, marg);
    chunk_sums_kernel<<<dim3(NCH, H_HEADS), b256, 0, stream>>>(kf, vh, Ac, bc);
    prefix_kernel<<<dim3(H_HEADS), b256, 0, stream>>>(Ac, bc, Sx, sx);
    lin_combine_kernel<<<dim3(NCH, H_HEADS), b256, 0, stream>>>(qf, kf, vh, Sx, sx, marg, att);
    wv_gather_kernel<<<dim3(T_SEQ / 4, H_HEADS), b256, 0, stream>>>(clist, critcnt, vh, att);
    out_proj_kernel<<<dim3(32, 8), b256, 0, stream>>>(att, wo, bo, out);
}

// Round 6
// 377.013 us; speedup vs baseline: 1.0605x; 1.0605x over previous
//
#include <hip/hip_runtime.h>
#include <math.h>

#define T_SEQ 2048
#define D_MODEL 512
#define H_HEADS 8
#define HD 64
#define NCH 32      // number of chunks
#define CSZ 64      // chunk size  (NCH*CSZ == T_SEQ)
#define CAP 192     // max stored critical entries per row (generic count = 103)

// order-preserving float<->u32 key transforms
__device__ __forceinline__ unsigned f2k(float f) {
    unsigned u = __float_as_uint(f);
    return (u & 0x80000000u) ? ~u : (u | 0x80000000u);
}
__device__ __forceinline__ float k2f(unsigned k) {
    unsigned u = (k & 0x80000000u) ? (k & 0x7fffffffu) : ~k;
    return __uint_as_float(u);
}

// ---------------- K1: QKV projection (x @ W.T + b), head-major store + phi ----------------
// grid (32, 8, 3), block 256
__global__ __launch_bounds__(256) void proj_qkv_kernel(
    const float* __restrict__ x,
    const float* __restrict__ wq, const float* __restrict__ bq,
    const float* __restrict__ wk, const float* __restrict__ bk,
    const float* __restrict__ wv, const float* __restrict__ bv,
    float* __restrict__ qh, float* __restrict__ kh, float* __restrict__ vh,
    float* __restrict__ qf, float* __restrict__ kf)
{
    const int which = blockIdx.z;
    const float* W    = (which == 0) ? wq : (which == 1) ? wk : wv;
    const float* bias = (which == 0) ? bq : (which == 1) ? bk : bv;
    float* outh = (which == 0) ? qh : (which == 1) ? kh : vh;
    float* outf = (which == 0) ? qf : (which == 1) ? kf : nullptr;

    __shared__ float As[64][33];
    __shared__ float Bs[64][33];
    const int tid = threadIdx.x;
    const int m0 = blockIdx.x * 64;
    const int n0 = blockIdx.y * 64;
    const int rb = (tid >> 4) * 4;
    const int cb = (tid & 15) * 4;

    float acc[4][4] = {};
    for (int k0 = 0; k0 < D_MODEL; k0 += 32) {
        for (int l = 0; l < 2; ++l) {
            int p = tid + l * 256;          // 0..511 float4 slots (64 rows x 8)
            int row = p >> 3;
            int c4 = (p & 7) * 4;
            float4 av = *(const float4*)(x + (size_t)(m0 + row) * D_MODEL + k0 + c4);
            As[row][c4 + 0] = av.x; As[row][c4 + 1] = av.y;
            As[row][c4 + 2] = av.z; As[row][c4 + 3] = av.w;
            float4 wv4 = *(const float4*)(W + (size_t)(n0 + row) * D_MODEL + k0 + c4);
            Bs[row][c4 + 0] = wv4.x; Bs[row][c4 + 1] = wv4.y;
            Bs[row][c4 + 2] = wv4.z; Bs[row][c4 + 3] = wv4.w;
        }
        __syncthreads();
        #pragma unroll
        for (int kk = 0; kk < 32; ++kk) {
            float ar[4], br[4];
            #pragma unroll
            for (int i = 0; i < 4; ++i) ar[i] = As[rb + i][kk];
            #pragma unroll
            for (int j = 0; j < 4; ++j) br[j] = Bs[cb + j][kk];
            #pragma unroll
            for (int i = 0; i < 4; ++i)
                #pragma unroll
                for (int j = 0; j < 4; ++j)
                    acc[i][j] = fmaf(ar[i], br[j], acc[i][j]);
        }
        __syncthreads();
    }
    #pragma unroll
    for (int i = 0; i < 4; ++i) {
        int m = m0 + rb + i;
        #pragma unroll
        for (int j = 0; j < 4; ++j) {
            int n = n0 + cb + j;
            float v = acc[i][j] + bias[n];
            int h = n >> 6, d = n & 63;
            size_t idx = ((size_t)(h * T_SEQ) + m) * HD + d;
            outh[idx] = v;
            if (outf) outf[idx] = (v > 0.f) ? (v + 1.f) : expf(v);  // elu+1
        }
    }
}

// ---------------- K6: output projection (att @ wo.T + bo) ----------------
// grid (32, 8), block 256
__global__ __launch_bounds__(256) void out_proj_kernel(
    const float* __restrict__ att, const float* __restrict__ wo,
    const float* __restrict__ bo, float* __restrict__ out)
{
    __shared__ float As[64][33];
    __shared__ float Bs[64][33];
    const int tid = threadIdx.x;
    const int m0 = blockIdx.x * 64;
    const int n0 = blockIdx.y * 64;
    const int rb = (tid >> 4) * 4;
    const int cb = (tid & 15) * 4;

    float acc[4][4] = {};
    for (int k0 = 0; k0 < D_MODEL; k0 += 32) {
        for (int l = 0; l < 2; ++l) {
            int p = tid + l * 256;
            int row = p >> 3;
            int c4 = (p & 7) * 4;
            float4 av = *(const float4*)(att + (size_t)(m0 + row) * D_MODEL + k0 + c4);
            As[row][c4 + 0] = av.x; As[row][c4 + 1] = av.y;
            As[row][c4 + 2] = av.z; As[row][c4 + 3] = av.w;
            float4 wv4 = *(const float4*)(wo + (size_t)(n0 + row) * D_MODEL + k0 + c4);
            Bs[row][c4 + 0] = wv4.x; Bs[row][c4 + 1] = wv4.y;
            Bs[row][c4 + 2] = wv4.z; Bs[row][c4 + 3] = wv4.w;
        }
        __syncthreads();
        #pragma unroll
        for (int kk = 0; kk < 32; ++kk) {
            float ar[4], br[4];
            #pragma unroll
            for (int i = 0; i < 4; ++i) ar[i] = As[rb + i][kk];
            #pragma unroll
            for (int j = 0; j < 4; ++j) br[j] = Bs[cb + j][kk];
            #pragma unroll
            for (int i = 0; i < 4; ++i)
                #pragma unroll
                for (int j = 0; j < 4; ++j)
                    acc[i][j] = fmaf(ar[i], br[j], acc[i][j]);
        }
        __syncthreads();
    }
    #pragma unroll
    for (int i = 0; i < 4; ++i) {
        int m = m0 + rb + i;
        #pragma unroll
        for (int j = 0; j < 4; ++j) {
            int n = n0 + cb + j;
            out[(size_t)m * D_MODEL + n] = acc[i][j] + bo[n];
        }
    }
}

// ---------------- K2a: S = Q K^T / 8, per head, 64x64 tiles ----------------
// grid (32 jtile, 32 ttile, 8 head), block 256
__global__ __launch_bounds__(256) void qk_gemm_kernel(
    const float* __restrict__ qh, const float* __restrict__ kh, float* __restrict__ S)
{
    __shared__ float As[64][65];   // Q rows (t)
    __shared__ float Bs[64][65];   // K rows (j)
    const int tid = threadIdx.x;
    const int n0 = blockIdx.x * 64;   // key index j
    const int m0 = blockIdx.y * 64;   // query index t
    const int h  = blockIdx.z;
    const float* qb = qh + (size_t)h * T_SEQ * HD;
    const float* kb = kh + (size_t)h * T_SEQ * HD;

    for (int l = 0; l < 4; ++l) {
        int p = tid + l * 256;            // 1024 float4 = 64 rows x 16
        int row = p >> 4, c4 = (p & 15) * 4;
        float4 a = *(const float4*)(qb + (size_t)(m0 + row) * HD + c4);
        As[row][c4 + 0] = a.x; As[row][c4 + 1] = a.y; As[row][c4 + 2] = a.z; As[row][c4 + 3] = a.w;
        float4 b = *(const float4*)(kb + (size_t)(n0 + row) * HD + c4);
        Bs[row][c4 + 0] = b.x; Bs[row][c4 + 1] = b.y; Bs[row][c4 + 2] = b.z; Bs[row][c4 + 3] = b.w;
    }
    __syncthreads();

    const int rb = (tid >> 4) * 4;
    const int cb = (tid & 15) * 4;
    float acc[4][4] = {};
    #pragma unroll 16
    for (int kk = 0; kk < HD; ++kk) {
        float ar[4], br[4];
        #pragma unroll
        for (int i = 0; i < 4; ++i) ar[i] = As[rb + i][kk];
        #pragma unroll
        for (int j = 0; j < 4; ++j) br[j] = Bs[cb + j][kk];
        #pragma unroll
        for (int i = 0; i < 4; ++i)
            #pragma unroll
            for (int j = 0; j < 4; ++j)
                acc[i][j] = fmaf(ar[i], br[j], acc[i][j]);
    }
    #pragma unroll
    for (int i = 0; i < 4; ++i) {
        float4 o;
        o.x = acc[i][0] * 0.125f; o.y = acc[i][1] * 0.125f;
        o.z = acc[i][2] * 0.125f; o.w = acc[i][3] * 0.125f;
        *(float4*)(S + ((size_t)h * T_SEQ + m0 + rb + i) * T_SEQ + n0 + cb) = o;
    }
}

// ---------------- K2b: per-row exact quantiles + critical-list compaction ----------------
// grid (T_SEQ/4, 8), block 256; wave w handles row blockIdx.x*4 + w
// hist[] is WAVE-PRIVATE (indexed by r) -> no __syncthreads anywhere.
// clist stores UNNORMALIZED weights; 1/z applied in wv_gather.
__global__ __launch_bounds__(256) void select_kernel(
    const float* __restrict__ S, float2* __restrict__ clist,
    int* __restrict__ critcnt, float* __restrict__ marg, float* __restrict__ rowinv)
{
    const int h = blockIdx.y;
    const int r = threadIdx.x >> 6;
    const int lane = threadIdx.x & 63;
    const int t = blockIdx.x * 4 + r;
    __shared__ unsigned hist[4][2][256];

    const float* srow = S + ((size_t)h * T_SEQ + t) * T_SEQ;
    unsigned kr[32];
    #pragma unroll
    for (int u = 0; u < 8; ++u) {
        float4 f = *(const float4*)(srow + (size_t)(lane + u * 64) * 4);
        kr[u * 4 + 0] = f2k(f.x); kr[u * 4 + 1] = f2k(f.y);
        kr[u * 4 + 2] = f2k(f.z); kr[u * 4 + 3] = f2k(f.w);
    }

    const unsigned rankv[2] = {204u, 1944u};
    unsigned pfx[2] = {0u, 0u}, base[2] = {0u, 0u};
    for (int p = 0; p < 4; ++p) {
        const int sh = 24 - 8 * p;
        #pragma unroll
        for (int q = 0; q < 4; ++q) {
            hist[r][0][lane * 4 + q] = 0u;
            hist[r][1][lane * 4 + q] = 0u;
        }
        const bool dup = (p == 0) || (pfx[0] == pfx[1]);
        if (p == 0) {
            #pragma unroll
            for (int u = 0; u < 32; ++u)
                atomicAdd(&hist[r][0][(kr[u] >> 24)], 1u);
        } else {
            #pragma unroll
            for (int u = 0; u < 32; ++u) {
                unsigned k = kr[u];
                unsigned hi = k >> (sh + 8);
                unsigned bin = (k >> sh) & 255u;
                if (hi == pfx[0]) atomicAdd(&hist[r][0][bin], 1u);
                if (!dup && hi == pfx[1]) atomicAdd(&hist[r][1][bin], 1u);
            }
        }
        #pragma unroll
        for (int si = 0; si < 2; ++si) {
            const unsigned* hh = hist[r][dup ? 0 : si];
            unsigned c0 = hh[lane * 4 + 0], c1 = hh[lane * 4 + 1];
            unsigned c2 = hh[lane * 4 + 2], c3 = hh[lane * 4 + 3];
            unsigned lsum = c0 + c1 + c2 + c3;
            unsigned incl = lsum;
            #pragma unroll
            for (int off = 1; off < 64; off <<= 1) {
                unsigned tv = __shfl_up(incl, off);
                if (lane >= off) incl += tv;
            }
            unsigned e0 = incl - lsum;
            unsigned e1 = e0 + c0, e2 = e1 + c1, e3 = e2 + c2;
            unsigned rr = rankv[si] - base[si];
            int bin = -1; unsigned nb = 0u;
            if (rr >= e0 && rr < e0 + c0)      { bin = lane * 4 + 0; nb = e0; }
            else if (rr >= e1 && rr < e1 + c1) { bin = lane * 4 + 1; nb = e1; }
            else if (rr >= e2 && rr < e2 + c2) { bin = lane * 4 + 2; nb = e2; }
            else if (rr >= e3 && rr < e3 + c3) { bin = lane * 4 + 3; nb = e3; }
            unsigned long long bal = __ballot(bin >= 0);
            int src = __ffsll((unsigned long long)bal) - 1;
            bin = __shfl(bin, src);
            nb  = __shfl(nb, src);
            pfx[si] = (pfx[si] << 8) | (unsigned)bin;
            base[si] += nb;
        }
    }

    const unsigned kth0 = pfx[0], kth1 = pfx[1];
    unsigned cle0 = 0, cle1 = 0, mng0 = 0xffffffffu, mng1 = 0xffffffffu, mx = 0u;
    #pragma unroll
    for (int u = 0; u < 32; ++u) {
        unsigned k = kr[u];
        mx = max(mx, k);
        if (k <= kth0) cle0++; else mng0 = min(mng0, k);
        if (k <= kth1) cle1++; else mng1 = min(mng1, k);
    }
    #pragma unroll
    for (int off = 32; off > 0; off >>= 1) {
        cle0 += (unsigned)__shfl_xor(cle0, off);
        cle1 += (unsigned)__shfl_xor(cle1, off);
        mng0 = min(mng0, (unsigned)__shfl_xor(mng0, off));
        mng1 = min(mng1, (unsigned)__shfl_xor(mng1, off));
        mx   = max(mx,   (unsigned)__shfl_xor(mx, off));
    }
    const float v204  = k2f(kth0);
    const float v205  = (cle0 > 205u) ? v204 : k2f(mng0);
    const float v1944 = k2f(kth1);
    const float v1945 = (cle1 > 1945u) ? v1944 : k2f(mng1);
    const float skip_th = v204 * 0.30f + v205 * 0.70f;
    const float crit_th = v1944 * 0.35f + v1945 * 0.65f;
    const float m = k2f(mx);

    // ---- fused pass: compaction (unnormalized w), z accumulation, marginal count ----
    float2* lrow = clist + ((size_t)h * T_SEQ + t) * CAP;
    float z = 0.f;
    unsigned mc = 0u;
    unsigned bcnt = 0;
    const unsigned long long pm = (lane == 0) ? 0ull : (~0ull >> (64 - lane));
    #pragma unroll
    for (int u8 = 0; u8 < 8; ++u8) {
        #pragma unroll
        for (int q = 0; q < 4; ++q) {
            float sv = k2f(kr[u8 * 4 + q]);
            bool crit = sv > crit_th;
            bool skip = sv < skip_th;
            if (!crit && !skip) mc++;
            unsigned long long bal = __ballot(crit);
            if (crit) {
                float w = __expf(sv - m);
                z += w;
                unsigned pos = bcnt + (unsigned)__popcll(bal & pm);
                if (pos < CAP) {
                    unsigned j = (unsigned)(4 * lane + 256 * u8 + q);
                    lrow[pos] = make_float2(w, __uint_as_float(j));
                }
            }
            bcnt += (unsigned)__popcll(bal);
        }
    }
    #pragma unroll
    for (int off = 32; off > 0; off >>= 1) {
        z += __shfl_xor(z, off);
        mc += (unsigned)__shfl_xor(mc, off);
    }
    if (lane == 0) {
        critcnt[(size_t)h * T_SEQ + t] = (int)min(bcnt, (unsigned)CAP);
        marg[(size_t)h * T_SEQ + t] = (float)mc * (1.f / (float)T_SEQ);
        rowinv[(size_t)h * T_SEQ + t] = (z > 0.f) ? (1.f / z) : 0.f;
    }
}

// ---------------- K2c: gather crit_out from compacted lists; att += invz * sum ----------------
// grid (T_SEQ/4, 8), block 256; wave per row
__global__ __launch_bounds__(256) void wv_gather_kernel(
    const float2* __restrict__ clist, const int* __restrict__ critcnt,
    const float* __restrict__ rowinv, const float* __restrict__ vh, float* __restrict__ att)
{
    const int h = blockIdx.y;
    const int r = threadIdx.x >> 6;
    const int lane = threadIdx.x & 63;
    const int t = blockIdx.x * 4 + r;
    const float* vb = vh + (size_t)h * T_SEQ * HD;
    const float2* lrow = clist + ((size_t)h * T_SEQ + t) * CAP;
    const int cnt = critcnt[(size_t)h * T_SEQ + t];
    const float invz = rowinv[(size_t)h * T_SEQ + t];

    float acc = 0.f;
    int i = 0;
    for (; i + 8 <= cnt; i += 8) {
        float2 e[8];
        #pragma unroll
        for (int q = 0; q < 8; ++q) e[q] = lrow[i + q];
        #pragma unroll
        for (int q = 0; q < 8; ++q) {
            unsigned j = __float_as_uint(e[q].y);
            acc = fmaf(e[q].x, vb[(size_t)j * HD + lane], acc);
        }
    }
    for (; i < cnt; ++i) {
        float2 e = lrow[i];
        unsigned j = __float_as_uint(e.y);
        acc = fmaf(e.x, vb[(size_t)j * HD + lane], acc);
    }
    att[(size_t)t * D_MODEL + h * HD + lane] += acc * invz;
}

// ---------------- K3: per-chunk sums A_c = sum kf x v, b_c = sum kf ----------------
// grid (NCH, 8), block 256
__global__ __launch_bounds__(256) void chunk_sums_kernel(
    const float* __restrict__ kf, const float* __restrict__ vh,
    float* __restrict__ Ac, float* __restrict__ bc)
{
    const int c = blockIdx.x, h = blockIdx.y;
    const int tid = threadIdx.x;
    __shared__ float kfl[CSZ][HD];
    __shared__ float vl[CSZ][HD];
    const size_t base = ((size_t)h * T_SEQ + c * CSZ) * HD;

    for (int l = 0; l < 4; ++l) {
        int p = tid + l * 256;            // float4 index over 64x16
        int row = p >> 4, c4 = (p & 15) * 4;
        *(float4*)&kfl[row][c4] = *(const float4*)(kf + base + (size_t)row * HD + c4);
        *(float4*)&vl[row][c4]  = *(const float4*)(vh + base + (size_t)row * HD + c4);
    }
    __syncthreads();

    const int d = tid >> 2, e0 = (tid & 3) * 16;
    float acc[16] = {};
    for (int u = 0; u < CSZ; ++u) {
        float a = kfl[u][d];
        #pragma unroll
        for (int i = 0; i < 16; ++i) acc[i] = fmaf(a, vl[u][e0 + i], acc[i]);
    }
    float* Adst = Ac + (((size_t)(h * NCH + c) * HD + d) * HD + e0);
    #pragma unroll
    for (int i = 0; i < 16; ++i) Adst[i] = acc[i];

    if (tid < HD) {
        float sum = 0.f;
        for (int u = 0; u < CSZ; ++u) sum += kfl[u][tid];
        bc[(size_t)(h * NCH + c) * HD + tid] = sum;
    }
}

// ---------------- K4: exclusive prefix over chunks ----------------
// grid (8), block 256
__global__ __launch_bounds__(256) void prefix_kernel(
    const float* __restrict__ Ac, const float* __restrict__ bc,
    float* __restrict__ Sx, float* __restrict__ sx)
{
    const int h = blockIdx.x;
    const int tid = threadIdx.x;
    float run[16];
    #pragma unroll
    for (int i = 0; i < 16; ++i) run[i] = 0.f;
    for (int c = 0; c < NCH; ++c) {
        const float* a = Ac + (size_t)(h * NCH + c) * 4096;
        float* sdst = Sx + (size_t)(h * NCH + c) * 4096;
        #pragma unroll
        for (int i = 0; i < 16; ++i) {
            int idx = tid + i * 256;
            sdst[idx] = run[i];
            run[i] += a[idx];
        }
    }
    if (tid < HD) {
        float rb = 0.f;
        for (int c = 0; c < NCH; ++c) {
            sx[(size_t)(h * NCH + c) * HD + tid] = rb;
            rb += bc[(size_t)(h * NCH + c) * HD + tid];
        }
    }
}

// ---------------- K5: intra-chunk causal linear attention; WRITES att ----------------
// grid (NCH, 8), block 256
__global__ __launch_bounds__(256) void lin_combine_kernel(
    const float* __restrict__ qf, const float* __restrict__ kf, const float* __restrict__ vh,
    const float* __restrict__ Sx, const float* __restrict__ sx,
    const float* __restrict__ marg, float* __restrict__ att)
{
    const int c = blockIdx.x, h = blockIdx.y;
    const int tid = threadIdx.x;
    __shared__ float Qs[CSZ][65];
    __shared__ float Ks[CSZ][65];   // reused to hold Ss after P is computed
    __shared__ float P[CSZ][66];
    __shared__ float svv[HD];
    __shared__ float coef[CSZ];

    const size_t base = ((size_t)h * T_SEQ + c * CSZ) * HD;
    for (int l = 0; l < 4; ++l) {
        int p = tid + l * 256;
        int row = p >> 4, c4 = (p & 15) * 4;
        *(float4*)&Qs[row][c4] = *(const float4*)(qf + base + (size_t)row * HD + c4);
        *(float4*)&Ks[row][c4] = *(const float4*)(kf + base + (size_t)row * HD + c4);
    }
    if (tid < HD) svv[tid] = sx[(size_t)(h * NCH + c) * HD + tid];
    __syncthreads();

    // P[t][u] = qf_t . kf_u  (zero above diagonal)
    {
        const int tq = tid >> 2, u0 = (tid & 3) * 16;
        float pr[16];
        #pragma unroll
        for (int i = 0; i < 16; ++i) pr[i] = 0.f;
        for (int d = 0; d < HD; ++d) {
            float qv = Qs[tq][d];
            #pragma unroll
            for (int i = 0; i < 16; ++i) pr[i] = fmaf(qv, Ks[u0 + i][d], pr[i]);
        }
        #pragma unroll
        for (int i = 0; i < 16; ++i) P[tq][u0 + i] = (u0 + i <= tq) ? pr[i] : 0.f;
    }
    __syncthreads();

    // denominator + coefficient (threads 0..63), and load Ss into Ks (all threads)
    if (tid < CSZ) {
        const int tq = tid;
        float den = 0.f;
        for (int d = 0; d < HD; ++d) den += Qs[tq][d] * svv[d];
        for (int u = 0; u <= tq; ++u) den += P[tq][u];
        den = fmaxf(den, 1e-6f);
        coef[tq] = marg[(size_t)h * T_SEQ + c * CSZ + tq] / den;
    }
    {
        const float* Sbase = Sx + (size_t)(h * NCH + c) * 4096;
        for (int l = 0; l < 4; ++l) {
            int p = tid + l * 256;
            int row = p >> 4, c4 = (p & 15) * 4;
            *(float4*)&Ks[row][c4] = *(const float4*)(Sbase + (size_t)row * HD + c4);
        }
    }
    __syncthreads();

    // lin_num = qf @ Ss + P @ v ; write out scaled (att = )
    {
        const int tq = tid >> 2, e0 = (tid & 3) * 16;
        float acc[16];
        #pragma unroll
        for (int i = 0; i < 16; ++i) acc[i] = 0.f;
        for (int d = 0; d < HD; ++d) {
            float qv = Qs[tq][d];
            #pragma unroll
            for (int i = 0; i < 16; ++i) acc[i] = fmaf(qv, Ks[d][e0 + i], acc[i]);
        }
        const float* vb = vh + base;
        for (int u = 0; u <= tq; ++u) {
            float pv = P[tq][u];
            #pragma unroll
            for (int i = 0; i < 16; ++i) acc[i] = fmaf(pv, vb[(size_t)u * HD + e0 + i], acc[i]);
        }
        const float cf = coef[tq];
        float* dst = att + (size_t)(c * CSZ + tq) * D_MODEL + h * HD + e0;
        #pragma unroll
        for (int i = 0; i < 16; ++i) dst[i] = acc[i] * cf;
    }
}

extern "C" void kernel_launch(void* const* d_in, const int* in_sizes, int n_in,
                              void* d_out, int out_size, void* d_ws, size_t ws_size,
                              hipStream_t stream)
{
    const float* x  = (const float*)d_in[0];
    const float* wq = (const float*)d_in[1];
    const float* bq = (const float*)d_in[2];
    const float* wk = (const float*)d_in[3];
    const float* bk = (const float*)d_in[4];
    const float* wv = (const float*)d_in[5];
    const float* bv = (const float*)d_in[6];
    const float* wo = (const float*)d_in[7];
    const float* bo = (const float*)d_in[8];
    float* out = (float*)d_out;

    float* ws = (float*)d_ws;
    const size_t NTD = (size_t)T_SEQ * D_MODEL;         // 1M floats
    const size_t NSS = (size_t)H_HEADS * T_SEQ * T_SEQ; // 33.5M floats (134 MB)
    const size_t NROW = (size_t)H_HEADS * T_SEQ;        // 16384
    float* S    = ws;
    float* qh   = S + NSS;
    float* kh   = qh + NTD;
    float* vh   = kh + NTD;
    float* qf   = vh + NTD;
    float* kf   = qf + NTD;
    float* att  = kf + NTD;
    float* Ac   = att + NTD;
    float* Sx   = Ac + NTD;
    float* bc   = Sx + NTD;                 // 16384
    float* sx   = bc + 16384;               // 16384
    float* marg = sx + 16384;               // 16384
    float2* clist = (float2*)(marg + 16384);        // NROW*CAP float2
    int* critcnt  = (int*)(clist + NROW * CAP);     // NROW ints
    float* rowinv = (float*)(critcnt + NROW);       // NROW floats

    dim3 b256(256);
    proj_qkv_kernel<<<dim3(32, 8, 3), b256, 0, stream>>>(x, wq, bq, wk, bk, wv, bv,
                                                         qh, kh, vh, qf, kf);
    qk_gemm_kernel<<<dim3(32, 32, 8), b256, 0, stream>>>(qh, kh, S);
    select_kernel<<<dim3(T_SEQ / 4, H_HEADS), b256, 0, stream>>>(S, clist, critcnt, marg, rowinv);
    chunk_sums_kernel<<<dim3(NCH, H_HEADS), b256, 0, stream>>>(kf, vh, Ac, bc);
    prefix_kernel<<<dim3(H_HEADS), b256, 0, stream>>>(Ac, bc, Sx, sx);
    lin_combine_kernel<<<dim3(NCH, H_HEADS), b256, 0, stream>>>(qf, kf, vh, Sx, sx, marg, att);
    wv_gather_kernel<<<dim3(T_SEQ / 4, H_HEADS), b256, 0, stream>>>(clist, critcnt, rowinv, vh, att);
    out_proj_kernel<<<dim3(32, 8), b256, 0, stream>>>(att, wo, bo, out);
}